// Round 4
// baseline (38.019 us; speedup 1.0000x reference)
//
#include <hip/hip_runtime.h>
#include <math.h>

// Realspace Ewald: pot = 2 * sum_{i<j} q_i q_j erf(d_ij/sqrt(2))/d_ij * NORM/(4pi)
// N=6144. VALU-bound. 3-term A&S 7.1.25 erf (|eps|<=2.5e-5, error budget ~0.9
// vs threshold 378). j-data via wave-uniform scalar loads (s_load_dwordx16 with
// unroll 16). Single kernel: active-tile 1D grid + last-block-done final reduce.

#if __has_builtin(__builtin_amdgcn_rsqf)
#define FRSQ(x) __builtin_amdgcn_rsqf(x)
#else
#define FRSQ(x) rsqrtf(x)
#endif
#if __has_builtin(__builtin_amdgcn_rcpf)
#define FRCP(x) __builtin_amdgcn_rcpf(x)
#else
#define FRCP(x) (1.0f / (x))
#endif
#if __has_builtin(__builtin_amdgcn_exp2f)
#define FEXP2(x) __builtin_amdgcn_exp2f(x)
#else
#define FEXP2(x) exp2f(x)
#endif

template <bool CHECK>
__device__ __forceinline__ float tile_sum(const float* __restrict__ q,
                                          const float* __restrict__ r,
                                          int jbeg, int jend, int i, float xi,
                                          float yi, float zi) {
  float acc = 0.f;
#pragma unroll 16
  for (int j = jbeg; j < jend; ++j) {
    // j is wave-uniform -> scalar s_load broadcasts, zero VALU cost
    float sx = r[3 * j];
    float sy = r[3 * j + 1];
    float sz = r[3 * j + 2];
    float qk = q[j];
    float dx = xi - sx;
    float dy = yi - sy;
    float dz = zi - sz;
    float d2 = fmaf(dx, dx, fmaf(dy, dy, dz * dz));
    bool take = true;
    if (CHECK) {
      take = (j > i);          // triangle + diagonal guard in one predicate
      d2 = take ? d2 : 1.0f;   // keep rsq well-defined
    }
    float rinv = FRSQ(d2);
    float d = d2 * rinv;
    // A&S 7.1.25: erf(x) = 1 - (a1 t + a2 t^2 + a3 t^3) e^{-x^2},
    // t = 1/(1+p x), x = d/sqrt(2); p/sqrt(2) = 0.47047/sqrt(2) = 0.33268097
    float t = FRCP(fmaf(0.33268097f, d, 1.0f));
    float e = FEXP2(d2 * -0.72134752044f);  // exp(-d2/2) = 2^(-d2*log2e/2)
    float p = fmaf(0.7478556f, t, -0.0958798f);
    p = fmaf(p, t, 0.3480242f);
    p = p * t;
    float w = fmaf(-p, e, 1.0f) * rinv;  // erf(d/sqrt2)/d
    float c = qk * w;
    if (CHECK) c = take ? c : 0.f;
    acc += c;
  }
  return acc;
}

__global__ __launch_bounds__(256) void ewald_fused(
    const float* __restrict__ q, const float* __restrict__ r,
    float* __restrict__ out, float* __restrict__ partial,
    unsigned int* __restrict__ counter, int n, int nblocks, float scale) {
  const int tid = threadIdx.x;
  const int bid = blockIdx.x;
  const int jslices = (n + 63) >> 6;

  // invert bid -> (ib, js). Active tiles for i-block ib: js in [4*ib, jslices).
  // Uniform scalar loop (<=24 iters), negligible.
  int ib = 0, cum = 0;
  while (true) {
    int c = jslices - 4 * ib;
    if (c <= 0 || cum + c > bid) break;
    cum += c;
    ++ib;
  }
  const int js = 4 * ib + (bid - cum);

  const int ibeg = ib << 8;
  const int jbeg = js << 6;
  const int jend = min(jbeg + 64, n);
  const bool pure_above = (jbeg >= ibeg + 256);  // all j > all i

  const int i = ibeg + tid;
  float qi = 0.f, xi = 0.f, yi = 0.f, zi = 0.f;
  if (i < n) {
    qi = q[i];
    xi = r[3 * i];
    yi = r[3 * i + 1];
    zi = r[3 * i + 2];
  }

  float acc;
  if (pure_above)
    acc = tile_sum<false>(q, r, jbeg, jend, i, xi, yi, zi);
  else
    acc = tile_sum<true>(q, r, jbeg, jend, i, xi, yi, zi);
  acc *= qi;

  // deterministic block reduce: wave shfl, then cross-wave via LDS
  for (int m = 32; m > 0; m >>= 1) acc += __shfl_xor(acc, m, 64);
  __shared__ float wsum[4];
  const int lane = tid & 63;
  const int wid = tid >> 6;
  if (lane == 0) wsum[wid] = acc;
  __syncthreads();

  // last-block-done final reduce (deterministic: fixed read order)
  __shared__ bool is_last;
  if (tid == 0) {
    partial[bid] = (wsum[0] + wsum[1]) + (wsum[2] + wsum[3]);
    __threadfence();  // make partial visible device-wide before count
    unsigned int old = atomicAdd(counter, 1u);
    is_last = (old == (unsigned int)(nblocks - 1));
  }
  __syncthreads();
  if (!is_last) return;

  __threadfence();  // acquire: see all partials
  float a2 = 0.f;
  for (int idx = tid; idx < nblocks; idx += 256) a2 += partial[idx];
  for (int m = 32; m > 0; m >>= 1) a2 += __shfl_xor(a2, m, 64);
  __shared__ float wsum2[4];
  if (lane == 0) wsum2[wid] = a2;
  __syncthreads();
  if (tid == 0)
    out[0] = ((wsum2[0] + wsum2[1]) + (wsum2[2] + wsum2[3])) * scale;
}

extern "C" void kernel_launch(void* const* d_in, const int* in_sizes, int n_in,
                              void* d_out, int out_size, void* d_ws,
                              size_t ws_size, hipStream_t stream) {
  const float* q = (const float*)d_in[0];  // [N,1] fp32
  const float* r = (const float*)d_in[1];  // [N,3] fp32
  const int n = in_sizes[0];
  float* out = (float*)d_out;
  float* partial = (float*)d_ws;
  unsigned int* counter = (unsigned int*)((char*)d_ws + (64 << 10));

  const int iblocks = (n + 255) / 256;
  const int jslices = (n + 63) / 64;
  int nblocks = 0;
  for (int ib = 0; ib < iblocks; ++ib) {
    int c = jslices - 4 * ib;
    if (c > 0) nblocks += c;
  }

  hipMemsetAsync(counter, 0, sizeof(unsigned int), stream);
  // 2 (triangle symmetry) * NORM/(2pi)/2 = NORM/(2pi)
  const float scale = (float)(90.0474 / (2.0 * M_PI));
  ewald_fused<<<nblocks, 256, 0, stream>>>(q, r, out, partial, counter, n,
                                           nblocks, scale);
}

// Round 5
// 21.378 us; speedup vs baseline: 1.7784x; 1.7784x over previous
//
#include <hip/hip_runtime.h>
#include <math.h>

// Realspace Ewald: pot = 2 * sum_{i<j} q_i q_j erf(d_ij/sqrt(2))/d_ij * NORM/(4pi)
// N=6144. VALU-bound. A&S 7.1.25 3-term erf (|eps|<=2.5e-5; absmax measured 0.0).
// j-tile (64 particles) staged ONCE per block in LDS; inner loop = ds_read_b128
// broadcast + math, no barriers, dual accumulators for ILP. Two kernels (fused
// memset-in-graph costs ~39us/replay -- R4 regression).

#if __has_builtin(__builtin_amdgcn_rsqf)
#define FRSQ(x) __builtin_amdgcn_rsqf(x)
#else
#define FRSQ(x) rsqrtf(x)
#endif
#if __has_builtin(__builtin_amdgcn_rcpf)
#define FRCP(x) __builtin_amdgcn_rcpf(x)
#else
#define FRCP(x) (1.0f / (x))
#endif
#if __has_builtin(__builtin_amdgcn_exp2f)
#define FEXP2(x) __builtin_amdgcn_exp2f(x)
#else
#define FEXP2(x) exp2f(x)
#endif

template <bool CHECK>
__device__ __forceinline__ void pair_body(const float4 v, int jj, int i,
                                          float xi, float yi, float zi,
                                          float& acc) {
  float dx = xi - v.x;
  float dy = yi - v.y;
  float dz = zi - v.z;
  float d2 = fmaf(dx, dx, fmaf(dy, dy, dz * dz));
  float qk = v.w;
  if (CHECK) {
    bool take = (jj > i);    // triangle + diagonal guard
    d2 = take ? d2 : 1.0f;   // keep rsq well-defined
    qk = take ? qk : 0.0f;
  }
  float rinv = FRSQ(d2);
  float d = d2 * rinv;
  // A&S 7.1.25: erf(x) = 1 - (a1 t + a2 t^2 + a3 t^3) e^{-x^2}, t=1/(1+p x),
  // x = d/sqrt(2); p/sqrt(2) = 0.47047/sqrt(2) = 0.33268097
  float t = FRCP(fmaf(0.33268097f, d, 1.0f));
  float e = FEXP2(d2 * -0.72134752044f);  // exp(-d2/2)
  float p = fmaf(0.7478556f, t, -0.0958798f);
  p = fmaf(p, t, 0.3480242f);
  p = p * t;
  float w = fmaf(-p, e, 1.0f) * rinv;  // erf(d/sqrt2)/d
  acc = fmaf(qk, w, acc);
}

template <bool CHECK>
__device__ __forceinline__ float tile_sum(const float4* __restrict__ tile,
                                          int cnt, int jbeg, int i, float xi,
                                          float yi, float zi) {
  float acc0 = 0.f, acc1 = 0.f;
  int k = 0;
#pragma unroll 8
  for (; k + 2 <= cnt; k += 2) {
    pair_body<CHECK>(tile[k], jbeg + k, i, xi, yi, zi, acc0);
    pair_body<CHECK>(tile[k + 1], jbeg + k + 1, i, xi, yi, zi, acc1);
  }
  if (k < cnt) pair_body<CHECK>(tile[k], jbeg + k, i, xi, yi, zi, acc0);
  return acc0 + acc1;
}

__global__ __launch_bounds__(256) void ewald_tri(
    const float* __restrict__ q, const float* __restrict__ r,
    float* __restrict__ partial, int n) {
  const int tid = threadIdx.x;
  const int ib = blockIdx.x;
  const int js = blockIdx.y;
  const int pidx = ib * gridDim.y + js;

  const int ibeg = ib << 8;
  const int jbeg = js << 6;
  const int jend = min(jbeg + 64, n);

  // tiles strictly below the diagonal: covered by the symmetric partner
  if (jend - 1 <= ibeg) {
    if (tid == 0) partial[pidx] = 0.f;
    return;
  }
  const bool pure_above = (jbeg >= ibeg + 256);

  // stage the whole j-tile once (64 particles, 1KB)
  __shared__ float4 tile[64];
  if (tid < 64) {
    int j = jbeg + tid;
    if (j < n) tile[tid] = make_float4(r[3 * j], r[3 * j + 1], r[3 * j + 2], q[j]);
  }

  const int i = ibeg + tid;
  float qi = 0.f, xi = 0.f, yi = 0.f, zi = 0.f;
  if (i < n) {
    qi = q[i];
    xi = r[3 * i];
    yi = r[3 * i + 1];
    zi = r[3 * i + 2];
  }
  __syncthreads();

  const int cnt = jend - jbeg;
  float acc;
  if (pure_above)
    acc = tile_sum<false>(tile, cnt, jbeg, i, xi, yi, zi);
  else
    acc = tile_sum<true>(tile, cnt, jbeg, i, xi, yi, zi);
  acc *= qi;

  // deterministic block reduce: wave shfl, then cross-wave via LDS
  for (int m = 32; m > 0; m >>= 1) acc += __shfl_xor(acc, m, 64);
  __shared__ float wsum[4];
  const int lane = tid & 63;
  const int wid = tid >> 6;
  if (lane == 0) wsum[wid] = acc;
  __syncthreads();
  if (tid == 0)
    partial[pidx] = (wsum[0] + wsum[1]) + (wsum[2] + wsum[3]);
}

__global__ __launch_bounds__(1024) void reduce_partials(
    const float* __restrict__ partial, float* __restrict__ out, int np,
    float scale) {
  const int tid = threadIdx.x;
  float acc = 0.f;
  for (int idx = tid; idx < np; idx += 1024) acc += partial[idx];
  for (int m = 32; m > 0; m >>= 1) acc += __shfl_xor(acc, m, 64);
  __shared__ float wsum[16];
  const int lane = tid & 63;
  const int wid = tid >> 6;
  if (lane == 0) wsum[wid] = acc;
  __syncthreads();
  if (tid == 0) {
    float s = 0.f;
    for (int w = 0; w < 16; ++w) s += wsum[w];
    out[0] = s * scale;
  }
}

extern "C" void kernel_launch(void* const* d_in, const int* in_sizes, int n_in,
                              void* d_out, int out_size, void* d_ws,
                              size_t ws_size, hipStream_t stream) {
  const float* q = (const float*)d_in[0];  // [N,1] fp32
  const float* r = (const float*)d_in[1];  // [N,3] fp32
  const int n = in_sizes[0];
  float* out = (float*)d_out;
  float* partial = (float*)d_ws;

  const int iblocks = (n + 255) / 256;
  const int jslices = (n + 63) / 64;
  dim3 grid(iblocks, jslices);
  ewald_tri<<<grid, 256, 0, stream>>>(q, r, partial, n);

  const int np = iblocks * jslices;
  // 2 (triangle symmetry) * NORM/(2pi)/2 = NORM/(2pi)
  const float scale = (float)(90.0474 / (2.0 * M_PI));
  reduce_partials<<<1, 1024, 0, stream>>>(partial, out, np, scale);
}

// Round 6
// 18.817 us; speedup vs baseline: 2.0205x; 1.1361x over previous
//
#include <hip/hip_runtime.h>
#include <math.h>

// Realspace Ewald: pot = 2 * sum_{i<j} q_i q_j erf(d_ij/sqrt(2))/d_ij * NORM/(4pi)
// N=6144. VALU-bound. erf via A&S 7.1.23 rational form (|eps|<=5e-4, output
// error ~7 vs threshold 378): NO exp2 -- per-pair = 9 VALU + rsq + rcp.
// sqrt(2) folded into poly coefficients. 64-particle j-tile staged once in LDS
// (broadcast ds_read, no inner barriers). 1D grid over the 1200 active
// triangle tiles only. Two kernels (fused memset-in-graph cost 39us: R4).

#if __has_builtin(__builtin_amdgcn_rsqf)
#define FRSQ(x) __builtin_amdgcn_rsqf(x)
#else
#define FRSQ(x) rsqrtf(x)
#endif
#if __has_builtin(__builtin_amdgcn_rcpf)
#define FRCP(x) __builtin_amdgcn_rcpf(x)
#else
#define FRCP(x) (1.0f / (x))
#endif

// A&S 7.1.23 coefficients pre-multiplied by (1/sqrt(2))^k so poly is in d:
// a1=0.278393 a2=0.230389 a3=0.000972 a4=0.078108, c=1/sqrt(2)
#define B1 0.19685360f  // a1*c
#define B2 0.11519450f  // a2*c^2
#define B3 0.00034366f  // a3*c^3
#define B4 0.01952700f  // a4*c^4

template <bool CHECK>
__device__ __forceinline__ void pair_body(const float4 v, int jj, int i,
                                          float xi, float yi, float zi,
                                          float& acc) {
  float dx = xi - v.x;
  float dy = yi - v.y;
  float dz = zi - v.z;
  float d2 = fmaf(dx, dx, fmaf(dy, dy, dz * dz));
  float qk = v.w;
  if (CHECK) {
    bool take = (jj > i);    // triangle + diagonal guard
    d2 = take ? d2 : 1.0f;   // keep rsq well-defined
    qk = take ? qk : 0.0f;
  }
  float rinv = FRSQ(d2);
  float d = d2 * rinv;
  // erf(d/sqrt2) = 1 - 1/(1 + b1 d + b2 d^2 + b3 d^3 + b4 d^4)^4
  float poly = fmaf(fmaf(fmaf(B4, d, B3), d, B2), d, B1);
  poly = fmaf(poly, d, 1.0f);
  float y = FRCP(poly);
  float y2 = y * y;
  float y4 = y2 * y2;
  float w = fmaf(-y4, rinv, rinv);  // erf(d/sqrt2)/d
  acc = fmaf(qk, w, acc);
}

template <bool CHECK>
__device__ __forceinline__ float tile_sum(const float4* __restrict__ tile,
                                          int cnt, int jbeg, int i, float xi,
                                          float yi, float zi) {
  float acc0 = 0.f, acc1 = 0.f;
  int k = 0;
#pragma unroll 8
  for (; k + 2 <= cnt; k += 2) {
    pair_body<CHECK>(tile[k], jbeg + k, i, xi, yi, zi, acc0);
    pair_body<CHECK>(tile[k + 1], jbeg + k + 1, i, xi, yi, zi, acc1);
  }
  if (k < cnt) pair_body<CHECK>(tile[k], jbeg + k, i, xi, yi, zi, acc0);
  return acc0 + acc1;
}

__global__ __launch_bounds__(256) void ewald_tri(
    const float* __restrict__ q, const float* __restrict__ r,
    float* __restrict__ partial, int n) {
  const int tid = threadIdx.x;
  const int bid = blockIdx.x;
  const int jslices = (n + 63) >> 6;

  // invert bid -> (ib, js): active js for i-block ib are [4*ib, jslices)
  int ib = 0, cum = 0;
  while (true) {
    int c = jslices - 4 * ib;
    if (c <= 0 || cum + c > bid) break;
    cum += c;
    ++ib;
  }
  const int js = 4 * ib + (bid - cum);

  const int ibeg = ib << 8;
  const int jbeg = js << 6;
  const int jend = min(jbeg + 64, n);
  const bool pure_above = (jbeg >= ibeg + 256);

  // stage the whole j-tile once (64 particles, 1KB)
  __shared__ float4 tile[64];
  if (tid < 64) {
    int j = jbeg + tid;
    if (j < n) tile[tid] = make_float4(r[3 * j], r[3 * j + 1], r[3 * j + 2], q[j]);
  }

  const int i = ibeg + tid;
  float qi = 0.f, xi = 0.f, yi = 0.f, zi = 0.f;
  if (i < n) {
    qi = q[i];
    xi = r[3 * i];
    yi = r[3 * i + 1];
    zi = r[3 * i + 2];
  }
  __syncthreads();

  const int cnt = jend - jbeg;
  float acc;
  if (pure_above)
    acc = tile_sum<false>(tile, cnt, jbeg, i, xi, yi, zi);
  else
    acc = tile_sum<true>(tile, cnt, jbeg, i, xi, yi, zi);
  acc *= qi;

  // deterministic block reduce: wave shfl, then cross-wave via LDS
  for (int m = 32; m > 0; m >>= 1) acc += __shfl_xor(acc, m, 64);
  __shared__ float wsum[4];
  const int lane = tid & 63;
  const int wid = tid >> 6;
  if (lane == 0) wsum[wid] = acc;
  __syncthreads();
  if (tid == 0)
    partial[bid] = (wsum[0] + wsum[1]) + (wsum[2] + wsum[3]);
}

__global__ __launch_bounds__(1024) void reduce_partials(
    const float* __restrict__ partial, float* __restrict__ out, int np,
    float scale) {
  const int tid = threadIdx.x;
  float acc = 0.f;
  for (int idx = tid; idx < np; idx += 1024) acc += partial[idx];
  for (int m = 32; m > 0; m >>= 1) acc += __shfl_xor(acc, m, 64);
  __shared__ float wsum[16];
  const int lane = tid & 63;
  const int wid = tid >> 6;
  if (lane == 0) wsum[wid] = acc;
  __syncthreads();
  if (tid == 0) {
    float s = 0.f;
    for (int w = 0; w < 16; ++w) s += wsum[w];
    out[0] = s * scale;
  }
}

extern "C" void kernel_launch(void* const* d_in, const int* in_sizes, int n_in,
                              void* d_out, int out_size, void* d_ws,
                              size_t ws_size, hipStream_t stream) {
  const float* q = (const float*)d_in[0];  // [N,1] fp32
  const float* r = (const float*)d_in[1];  // [N,3] fp32
  const int n = in_sizes[0];
  float* out = (float*)d_out;
  float* partial = (float*)d_ws;

  const int iblocks = (n + 255) / 256;
  const int jslices = (n + 63) / 64;
  int nblocks = 0;
  for (int ib = 0; ib < iblocks; ++ib) {
    int c = jslices - 4 * ib;
    if (c > 0) nblocks += c;
  }

  ewald_tri<<<nblocks, 256, 0, stream>>>(q, r, partial, n);

  // 2 (triangle symmetry) * NORM/(2pi)/2 = NORM/(2pi)
  const float scale = (float)(90.0474 / (2.0 * M_PI));
  reduce_partials<<<1, 1024, 0, stream>>>(partial, out, nblocks, scale);
}